// Round 1
// baseline (239.803 us; speedup 1.0000x reference)
//
#include <hip/hip_runtime.h>

#define B_    2
#define SEQ_  2048
#define H_    32
#define HKV_  8
#define D_    128
#define BLK_  64
#define NB_   32
#define LOCAL_ 16
#define VERT_  8

#define PSTR 72    // P LDS row stride (v1 fallback only)
#define NTASK 512
#define NBLOCK 256

typedef __attribute__((ext_vector_type(8))) short bf16x8;
typedef __attribute__((ext_vector_type(4))) float f32x4;
typedef __attribute__((ext_vector_type(16))) float f32x16;

__device__ __forceinline__ unsigned short f2bf(float f) {
    union { float f; unsigned u; } x; x.f = f;
    unsigned u = x.u;
    return (unsigned short)((u + 0x7FFFu + ((u >> 16) & 1u)) >> 16);
}

__device__ __forceinline__ unsigned pk2(float a, float b) {
#if defined(__has_builtin) && __has_builtin(__builtin_amdgcn_cvt_pk_bf16_f32)
    typedef __attribute__((ext_vector_type(2))) __bf16 bf2;
    bf2 r = __builtin_amdgcn_cvt_pk_bf16_f32(a, b);
    unsigned u; __builtin_memcpy(&u, &r, 4); return u;
#else
    return (unsigned)f2bf(a) | ((unsigned)f2bf(b) << 16);
#endif
}

// v_permlane32_swap_b32 a, b : new a[32:63] = old b[0:31]; new b[0:31] = old a[32:63].
__device__ __forceinline__ void pswap(unsigned &a, unsigned &b) {
#if defined(__has_builtin) && __has_builtin(__builtin_amdgcn_permlane32_swap)
    auto r = __builtin_amdgcn_permlane32_swap((int)a, (int)b, false, false);
    a = (unsigned)r[0]; b = (unsigned)r[1];
#else
    asm("v_permlane32_swap_b32 %0, %1" : "+v"(a), "+v"(b));
#endif
}

__device__ __forceinline__ f32x16 zero16() {
    f32x16 z;
#pragma unroll
    for (int i = 0; i < 16; ++i) z[i] = 0.f;
    return z;
}

__device__ __forceinline__ int next_valid(int qb, int j) {
    for (++j; j <= qb; ++j)
        if (((qb - j) < LOCAL_) || (((j + 1) & (VERT_ - 1)) == 0)) return j;
    return qb + 1;
}

// async global->LDS DMA, 16B/lane. ldsptr MUST be wave-uniform (HW places lane i at base+i*16).
__device__ __forceinline__ void dma16(const unsigned short* g, unsigned short* l) {
    __builtin_amdgcn_global_load_lds(
        (const __attribute__((address_space(1))) unsigned int*)g,
        (__attribute__((address_space(3))) unsigned int*)l, 16, 0, 0);
}

// ============ prepass: K -> bf16 swizzled rows; V -> bf16 transposed+swizzled tiles ============
// K_ws layout: [(b*8+hkv)*2048 + row][128], row's 16 16B-chunks stored at chunk^(row&15).
// V_ws layout: [(b*8+hkv)*32 + jb][d=0..127][64 pos], d-row's 8 16B-chunks stored at chunk^(d&7).
// (Both swizzles verified bank-optimal for the v3 32-row read pattern as well: for a wave b128
//  read, each 16B slot is hit exactly 4x -> minimum bank-cycles.)
__global__ __launch_bounds__(256)
void prepass_kernel(const float* __restrict__ kg, const float* __restrict__ vg,
                    unsigned short* __restrict__ Kws, unsigned short* __restrict__ Vws) {
    __shared__ unsigned short Vt[D_ * 72];   // [d][pos], padded
    const int bid = blockIdx.x;
    const int b   = bid >> 8;
    const int hkv = (bid >> 5) & 7;
    const int jb  = bid & 31;
    const int tid = threadIdx.x;
    const int rs  = HKV_ * D_;   // fp32 row stride

    const float* kbase = kg + ((size_t)(b * SEQ_ + jb * BLK_) * HKV_ + hkv) * D_;
    const float* vbase = vg + ((size_t)(b * SEQ_ + jb * BLK_) * HKV_ + hkv) * D_;
    unsigned short* Kdst = Kws + ((size_t)(b * 8 + hkv) * SEQ_ + jb * BLK_) * D_;
    unsigned short* Vdst = Vws + ((size_t)(b * 8 + hkv) * NB_ + jb) * (D_ * BLK_);

#pragma unroll
    for (int t = 0; t < 4; ++t) {           // K: 1024 chunks of 8 elems
        const int q = t * 256 + tid;
        const int row = q >> 4, c = q & 15;
        const float* p = kbase + (size_t)row * rs + c * 8;
        const float4 a = *(const float4*)p;
        const float4 d4 = *(const float4*)(p + 4);
        uint4 u = { pk2(a.x, a.y), pk2(a.z, a.w), pk2(d4.x, d4.y), pk2(d4.z, d4.w) };
        *(uint4*)&Kdst[row * 128 + ((c ^ (row & 15)) << 3)] = u;
    }
#pragma unroll
    for (int t = 0; t < 8; ++t) {           // V: load + transpose into LDS
        const int q = t * 256 + tid;
        const int pos = q >> 5, c4 = q & 31;
        const float4 v4 = *(const float4*)(vbase + (size_t)pos * rs + c4 * 4);
        const unsigned u0 = pk2(v4.x, v4.y), u1 = pk2(v4.z, v4.w);
        Vt[(c4 * 4 + 0) * 72 + pos] = (unsigned short)u0;
        Vt[(c4 * 4 + 1) * 72 + pos] = (unsigned short)(u0 >> 16);
        Vt[(c4 * 4 + 2) * 72 + pos] = (unsigned short)u1;
        Vt[(c4 * 4 + 3) * 72 + pos] = (unsigned short)(u1 >> 16);
    }
    __syncthreads();
#pragma unroll
    for (int t = 0; t < 4; ++t) {           // V out: 1024 chunks of 8 pos
        const int q = t * 256 + tid;
        const int d = q >> 3, c = q & 7;
        const uint2 q0 = *(const uint2*)&Vt[d * 72 + c * 8];
        const uint2 q1 = *(const uint2*)&Vt[d * 72 + c * 8 + 4];
        uint4 u = { q0.x, q0.y, q1.x, q1.y };
        *(uint4*)&Vdst[d * 64 + ((c ^ (d & 7)) << 3)] = u;
    }
}

// ============ main kernel v3: 32x32 MFMA, swapped QK^T, in-register P ============
// 8 waves/block (512 thr): wave = hsub*2 + rt2; hsub in [0,4) = head within GQA group,
// rt2 in {0,1} = 32-row tile within the 64-row query block.
//
// QK^T swapped: S^T = mfma_32x32x16(A=K, B=Q). C-layout (verified): col = lane&31 = q-row,
// row = crow(r,h) = (r&3)+8*(r>>2)+4*h (h = lane>>5) = k-col. So each lane holds a full
// P row (its q) in registers -> no P LDS round-trip.
//
// P(f32) -> PV A-frags (pos = kc*16 + h'*8 + e; element e maps to source half h_src=e>>2,
// reg r = (e&3)+8*(kc&1)+4h'):  A_i = pk2(p[b0+2i],p[b0+2i+1]), B_i = pk2(p[b0+4+2i],p[b0+4+2i+1]),
// pswap(A_i,B_i) ->  A_i becomes frag word i (both halves), B_i becomes frag word 2+i.
//
// l accumulated via mfma(pa, ones) -> same C-layout rows as O, epilogue is lane-local.
__global__ __launch_bounds__(512, 2)
void sparse_attn_v3(const float* __restrict__ qg, float* __restrict__ outg,
                    const unsigned short* __restrict__ Kws,
                    const unsigned short* __restrict__ Vws,
                    unsigned* __restrict__ ctr) {
    __shared__ __align__(16) unsigned short Kb[2][BLK_ * D_];   // 2 x 16 KB
    __shared__ __align__(16) unsigned short Vb[2][D_ * BLK_];   // 2 x 16 KB
    __shared__ unsigned taskLds;

    const int tid  = threadIdx.x;
    const int wave = tid >> 6;
    const int lane = tid & 63;
    const int q5   = lane & 31;       // q-row within 32-row tile / d-col within 32 / K-row within 32
    const int h    = lane >> 5;       // lane half
    const int hsub = wave >> 1;
    const int rt2  = wave & 1;

    // lane-constant swizzled 16B-chunk offsets (in ushort elems)
    int cskA[8];                      // K read: chunk c = dk*2+h, stored at c^(row&15)
#pragma unroll
    for (int dk = 0; dk < 8; ++dk) cskA[dk] = ((((dk * 2) | h) ^ (lane & 15)) << 3);
    int csvB[4];                      // V read: chunk c = kc*2+h, stored at c^(d&7)
#pragma unroll
    for (int kc = 0; kc < 4; ++kc) csvB[kc] = ((((kc * 2) | h) ^ (lane & 7)) << 3);

    const float c2 = 0.12751649736230723f;   // (1/sqrt(128)) * log2(e)
    const short oneb = (short)0x3F80;
    const bf16x8 ones = {oneb, oneb, oneb, oneb, oneb, oneb, oneb, oneb};

    for (;;) {
        __syncthreads();
        if (tid == 0) taskLds = atomicAdd(ctr, 1u);
        __syncthreads();
        const unsigned t = taskLds;
        if (t >= NTASK) break;

        const int qb  = 31 - (int)(t >> 4);   // LPT: big tasks first
        const int bh  = (int)(t & 15);
        const int b   = bh >> 3;
        const int hkv = bh & 7;
        const int head = hkv * 4 + hsub;

        const unsigned short* Kbh = Kws + (size_t)(b * 8 + hkv) * SEQ_ * D_;
        const unsigned short* Vbh = Vws + (size_t)(b * 8 + hkv) * NB_ * (D_ * BLK_);

        int j = next_valid(qb, -1);
        // issue first tile DMA into buf0 (latency hidden behind Q load/convert)
        {
            const size_t off = (size_t)j * (BLK_ * D_);
#pragma unroll
            for (int i = 0; i < 2; ++i) {
                dma16(Kbh + off + i * 4096 + tid * 8, &Kb[0][i * 4096 + wave * 512]);
                dma16(Vbh + off + i * 4096 + tid * 8, &Vb[0][i * 4096 + wave * 512]);
            }
        }

        // ---- Q fragments (B-operand layout): q-col = q5, d = dk*16 + h*8 + e
        bf16x8 qf[8];
        {
            const int row = qb * BLK_ + rt2 * 32 + q5;
            const float* qp = qg + ((size_t)(b * SEQ_ + row) * H_ + head) * D_ + h * 8;
#pragma unroll
            for (int dk = 0; dk < 8; ++dk) {
                const float4 a = *(const float4*)(qp + dk * 16);
                const float4 c = *(const float4*)(qp + dk * 16 + 4);
                uint4 u = { pk2(a.x, a.y), pk2(a.z, a.w), pk2(c.x, c.y), pk2(c.z, c.w) };
                __builtin_memcpy(&qf[dk], &u, 16);
            }
        }

        f32x16 lacc = zero16();
        f32x16 o_acc[4];
#pragma unroll
        for (int dt = 0; dt < 4; ++dt) o_acc[dt] = zero16();

        __syncthreads();   // drains first DMA (vmcnt(0)) + syncs all waves
        int it = 0;
        while (j <= qb) {
            const int jn = next_valid(qb, j);
            const int cur = it & 1;
            if (jn <= qb) {   // issue next tile into the other buffer (wave-uniform branch)
                const size_t off = (size_t)jn * (BLK_ * D_);
#pragma unroll
                for (int i = 0; i < 2; ++i) {
                    dma16(Kbh + off + i * 4096 + tid * 8, &Kb[cur ^ 1][i * 4096 + wave * 512]);
                    dma16(Vbh + off + i * 4096 + tid * 8, &Vb[cur ^ 1][i * 4096 + wave * 512]);
                }
            }

            const bool diag  = (j == qb);
            const bool diagw = diag && (rt2 == 0);   // upper 32 k-cols fully masked -> skip mt=1

            // ---- S^T = K Q^T (swapped), conflict-free swizzled b128 reads
            const unsigned short* kb = Kb[cur];
            f32x16 s0 = zero16(), s1 = zero16();
            {
                const unsigned short* k0r = kb + q5 * 128;           // mt=0: k-cols 0..31
                const unsigned short* k1r = kb + (32 + q5) * 128;    // mt=1: k-cols 32..63
#pragma unroll
                for (int dk = 0; dk < 8; ++dk) {
                    const bf16x8 kf0 = *(const bf16x8*)(k0r + cskA[dk]);
                    s0 = __builtin_amdgcn_mfma_f32_32x32x16_bf16(kf0, qf[dk], s0, 0, 0, 0);
                }
                if (!diagw) {
#pragma unroll
                    for (int dk = 0; dk < 8; ++dk) {
                        const bf16x8 kf1 = *(const bf16x8*)(k1r + cskA[dk]);
                        s1 = __builtin_amdgcn_mfma_f32_32x32x16_bf16(kf1, qf[dk], s1, 0, 0, 0);
                    }
                }
            }

            if (diag) {   // token-level causal mask on the triangular tile (mt == rt2)
                if (rt2 == 0) {
#pragma unroll
                    for (int r = 0; r < 16; ++r) {
                        const int crow = (r & 3) + 8 * (r >> 2) + 4 * h;
                        if (crow > q5) s0[r] = -INFINITY;
                    }
                } else {
#pragma unroll
                    for (int r = 0; r < 16; ++r) {
                        const int crow = (r & 3) + 8 * (r >> 2) + 4 * h;
                        if (crow > q5) s1[r] = -INFINITY;
                    }
                }
            }

            // ---- P = exp2(c2*S) in place (constant-offset softmax, no max/rescale)
#pragma unroll
            for (int r = 0; r < 16; ++r) s0[r] = exp2f(s0[r] * c2);
            if (!diagw) {
#pragma unroll
                for (int r = 0; r < 16; ++r) s1[r] = exp2f(s1[r] * c2);
            }

            // ---- P -> bf16 PV A-frags entirely in registers; l += P (via ones-MFMA)
            bf16x8 pa[4];
#pragma unroll
            for (int kc = 0; kc < 4; ++kc) {
                if (kc >= 2 && diagw) continue;
                const f32x16 &pp = (kc >= 2) ? s1 : s0;
                const int b0 = (kc & 1) * 8;
                unsigned A0 = pk2(pp[b0 + 0], pp[b0 + 1]);
                unsigned B0 = pk2(pp[b0 + 4], pp[b0 + 5]);
                unsigned A1 = pk2(pp[b0 + 2], pp[b0 + 3]);
                unsigned B1 = pk2(pp[b0 + 6], pp[b0 + 7]);
                pswap(A0, B0);   // A0 -> frag word0, B0 -> frag word2
                pswap(A1, B1);   // A1 -> frag word1, B1 -> frag word3
                uint4 u = { A0, A1, B0, B1 };
                __builtin_memcpy(&pa[kc], &u, 16);
                lacc = __builtin_amdgcn_mfma_f32_32x32x16_bf16(pa[kc], ones, lacc, 0, 0, 0);
            }

            // ---- O += P V (swizzled conflict-free b128 reads; d-col = dt*32 + q5)
            const unsigned short* vb = Vb[cur];
#pragma unroll
            for (int dt = 0; dt < 4; ++dt) {
                const unsigned short* vrow = vb + (dt * 32 + q5) * 64;
#pragma unroll
                for (int kc = 0; kc < 4; ++kc) {
                    if (kc >= 2 && diagw) continue;
                    const bf16x8 vf = *(const bf16x8*)(vrow + csvB[kc]);
                    o_acc[dt] = __builtin_amdgcn_mfma_f32_32x32x16_bf16(pa[kc], vf, o_acc[dt], 0, 0, 0);
                }
            }

            __syncthreads();   // vmcnt(0) drain waits the DMA issued ABOVE (full compute behind it)
            j = jn; ++it;
        }

        // ---- epilogue: O rows and l rows share the same C-layout -> lane-local normalize
        const int rowbase = qb * BLK_ + rt2 * 32;
#pragma unroll
        for (int r = 0; r < 16; ++r) {
            const int row = rowbase + (r & 3) + 8 * (r >> 2) + 4 * h;
            const float inv = 1.0f / lacc[r];
            float* op = outg + ((size_t)(b * SEQ_ + row) * H_ + head) * D_ + q5;
            op[0]  = o_acc[0][r] * inv;
            op[32] = o_acc[1][r] * inv;
            op[64] = o_acc[2][r] * inv;
            op[96] = o_acc[3][r] * inv;
        }
    }
}

// ============ fallback (no workspace): round-4 kernel, unchanged ============
#define KSTR 136
#define VSTR 72
__global__ __launch_bounds__(1024)
void sparse_attn_v1(const float* __restrict__ qg, const float* __restrict__ kg,
                    const float* __restrict__ vg, float* __restrict__ outg,
                    unsigned* __restrict__ ctr) {
    __shared__ __align__(16) unsigned short Klds[BLK_ * KSTR];
    __shared__ __align__(16) unsigned short Vlds[D_ * VSTR];
    __shared__ __align__(16) unsigned short Plds[16 * 16 * PSTR];
    __shared__ unsigned taskLds;

    const int tid  = threadIdx.x;
    const int wave = tid >> 6;
    const int lane = tid & 63;
    const int l15  = lane & 15;
    const int quad = lane >> 4;
    const int hsub = wave >> 2;
    const int rt   = wave & 3;

    const int srow0 = tid >> 5, srow1 = srow0 + 32;
    const int sc4   = tid & 31;
    const int kld0  = srow0 * KSTR + sc4 * 4, kld1 = srow1 * KSTR + sc4 * 4;
    const int vd    = sc4 * 4;
    const int vskew = (sc4 & 7) << 3;
    const int vp0   = (srow0 + vskew) & 63, vp1 = (srow1 + vskew) & 63;
    const size_t stoff0 = (size_t)srow0 * (HKV_ * D_) + sc4 * 4;
    const size_t stoff1 = (size_t)srow1 * (HKV_ * D_) + sc4 * 4;

    const float c2 = 0.12751649736230723f;
    const short oneb = (short)0x3F80;
    const bf16x8 ones = {oneb, oneb, oneb, oneb, oneb, oneb, oneb, oneb};
    unsigned short* pl = &Plds[wave * 16 * PSTR];

    for (;;) {
        __syncthreads();
        if (tid == 0) taskLds = atomicAdd(ctr, 1u);
        __syncthreads();
        const unsigned t = taskLds;
        if (t >= NTASK) break;
        const int qb  = 31 - (int)(t >> 4);
        const int bh  = (int)(t & 15);
        const int b   = bh >> 3;
        const int hkv = bh & 7;
        const int head = hkv * 4 + hsub;
        const float* kbase = kg + ((size_t)(b * SEQ_) * HKV_ + hkv) * D_;
        const float* vbase = vg + ((size_t)(b * SEQ_) * HKV_ + hkv) * D_;
        bf16x8 qf[4];
        {
            const int row = qb * BLK_ + rt * 16 + l15;
            const float* qp = qg + ((size_t)(b * SEQ_ + row) * H_ + head) * D_;
#pragma unroll
            for (int s = 0; s < 4; ++s) {
                const float4 a = *(const float4*)(qp + s * 32 + quad * 8);
                const float4 c = *(const float4*)(qp + s * 32 + quad * 8 + 4);
                uint4 u = { pk2(a.x, a.y), pk2(a.z, a.w), pk2(c.x, c.y), pk2(c.z, c.w) };
                __builtin_memcpy(&qf[s], &u, 16);
            }
        }
        f32x4 lacc = f32x4{0.f, 0.f, 0.f, 0.f};
        f32x4 o_acc[8];
#pragma unroll
        for (int t8 = 0; t8 < 8; ++t8) o_acc[t8] = f32x4{0.f, 0.f, 0.f, 0.f};
        int j = next_valid(qb, -1);
        float4 kpr0, kpr1, vpr0, vpr1;
        {
            const float* kp = kbase + (size_t)j * BLK_ * HKV_ * D_;
            const float* vp = vbase + (size_t)j * BLK_ * HKV_ * D_;
            kpr0 = *(const float4*)(kp + stoff0); kpr1 = *(const float4*)(kp + stoff1);
            vpr0 = *(const float4*)(vp + stoff0); vpr1 = *(const float4*)(vp + stoff1);
        }
        while (j <= qb) {
            const int jn = next_valid(qb, j);
            __syncthreads();
            {
                uint2 u0 = { pk2(kpr0.x, kpr0.y), pk2(kpr0.z, kpr0.w) };
                uint2 u1 = { pk2(kpr1.x, kpr1.y), pk2(kpr1.z, kpr1.w) };
                *(uint2*)&Klds[kld0] = u0;
                *(uint2*)&Klds[kld1] = u1;
                unsigned a0 = pk2(vpr0.x, vpr0.y), a1 = pk2(vpr0.z, vpr0.w);
                Vlds[(vd + 0) * VSTR + vp0] = (unsigned short)a0;
                Vlds[(vd + 1) * VSTR + vp0] = (unsigned short)(a0 >> 16);
                Vlds[(vd + 2) * VSTR + vp0] = (unsigned short)a1;
                Vlds[(vd + 3) * VSTR + vp0] = (unsigned short)(a1 >> 16);
                unsigned b0 = pk2(vpr1.x, vpr1.y), b1 = pk2(vpr1.z, vpr1.w);
                Vlds[(vd + 0) * VSTR + vp1] = (unsigned short)b0;
                Vlds[(vd + 1) * VSTR + vp1] = (unsigned short)(b0 >> 16);
                Vlds[(vd + 2) * VSTR + vp1] = (unsigned short)b1;
                Vlds[(vd + 3) * VSTR + vp1] = (unsigned short)(b1 >> 16);
            }
            __syncthreads();
            if (jn <= qb) {
                const float* kp = kbase + (size_t)jn * BLK_ * HKV_ * D_;
                const float* vp = vbase + (size_t)jn * BLK_ * HKV_ * D_;
                kpr0 = *(const float4*)(kp + stoff0); kpr1 = *(const float4*)(kp + stoff1);
                vpr0 = *(const float4*)(vp + stoff0); vpr1 = *(const float4*)(vp + stoff1);
            }
            f32x4 sacc[4];
#pragma unroll
            for (int t4 = 0; t4 < 4; ++t4) {
                f32x4 acc = f32x4{0.f, 0.f, 0.f, 0.f};
#pragma unroll
                for (int s = 0; s < 4; ++s) {
                    const bf16x8 kf = *(const bf16x8*)&Klds[(t4 * 16 + l15) * KSTR + s * 32 + quad * 8];
                    acc = __builtin_amdgcn_mfma_f32_16x16x32_bf16(qf[s], kf, acc, 0, 0, 0);
                }
                sacc[t4] = acc;
            }
            if (j == qb) {
                const int rowbase = rt * 16 + quad * 4;
#pragma unroll
                for (int t4 = 0; t4 < 4; ++t4) {
                    const int col = t4 * 16 + l15;
#pragma unroll
                    for (int r = 0; r < 4; ++r)
                        if (col > rowbase + r) sacc[t4][r] = -INFINITY;
                }
            }
#pragma unroll
            for (int t4 = 0; t4 < 4; ++t4) {
                const float p0 = exp2f(sacc[t4][0] * c2);
                const float p1 = exp2f(sacc[t4][1] * c2);
                const float p2 = exp2f(sacc[t4][2] * c2);
                const float p3 = exp2f(sacc[t4][3] * c2);
                const unsigned u01 = pk2(p0, p1), u23 = pk2(p2, p3);
                const int cb = t4 * 16 + l15;
                pl[(quad * 4 + 0) * PSTR + cb] = (unsigned short)u01;
                pl[(quad * 4 + 1) * PSTR + cb] = (unsigned short)(u01 >> 16);
                pl[(quad * 4 + 2) * PSTR + cb] = (unsigned short)u23;
                pl[(quad * 4 + 3) * PSTR + cb] = (unsigned short)(u23 >> 16);
            }
#pragma unroll
            for (int s2 = 0; s2 < 2; ++s2) {
                const bf16x8 pf = *(const bf16x8*)&pl[l15 * PSTR + s2 * 32 + quad * 8];
                lacc = __builtin_amdgcn_mfma_f32_16x16x32_bf16(pf, ones, lacc, 0, 0, 0);
                const int k0 = s2 * 32 + quad * 8;
#pragma unroll
                for (int t8 = 0; t8 < 8; ++t8) {
                    const int n  = t8 * 16 + l15;
                    const int p2 = (k0 + (((n >> 2) & 7) << 3)) & 63;
                    const bf16x8 vf = *(const bf16x8*)&Vlds[n * VSTR + p2];
                    o_acc[t8] = __builtin_amdgcn_mfma_f32_16x16x32_bf16(pf, vf, o_acc[t8], 0, 0, 0);
                }
            }
            j = jn;
        }
        const int orow = qb * BLK_ + rt * 16 + quad * 4;
#pragma unroll
        for (int r = 0; r < 4; ++r) {
            const float inv_l = 1.0f / lacc[r];
            float* op = outg + ((size_t)(b * SEQ_ + orow + r) * H_ + head) * D_;
#pragma unroll
            for (int t8 = 0; t8 < 8; ++t8)
                op[t8 * 16 + l15] = o_acc[t8][r] * inv_l;
        }
    }
}

extern "C" void kernel_launch(void* const* d_in, const int* in_sizes, int n_in,
                              void* d_out, int out_size, void* d_ws, size_t ws_size,
                              hipStream_t stream) {
    const float* q = (const float*)d_in[0];
    const float* k = (const float*)d_in[1];
    const float* v = (const float*)d_in[2];
    float* out = (float*)d_out;

    const size_t kws_elems = (size_t)B_ * HKV_ * SEQ_ * D_;   // 4,194,304 bf16
    const size_t need = 256 + 2 * kws_elems * sizeof(unsigned short);
    if (ws_size >= need) {
        unsigned short* Kws = (unsigned short*)((char*)d_ws + 256);
        unsigned short* Vws = Kws + kws_elems;
        hipMemsetAsync(d_ws, 0, 256, stream);
        prepass_kernel<<<dim3(B_ * HKV_ * NB_), dim3(256), 0, stream>>>(k, v, Kws, Vws);
        sparse_attn_v3<<<dim3(NBLOCK), dim3(512), 0, stream>>>(q, out, Kws, Vws, (unsigned*)d_ws);
    } else {
        hipMemsetAsync(d_ws, 0, sizeof(unsigned), stream);
        sparse_attn_v1<<<dim3(NBLOCK), dim3(1024), 0, stream>>>(q, k, v, out, (unsigned*)d_ws);
    }
}